// Round 8
// baseline (412.656 us; speedup 1.0000x reference)
//
#include <hip/hip_runtime.h>
#include <hip/hip_cooperative_groups.h>

namespace cg = cooperative_groups;

#define V_ 25000
#define F_ 8192
#define E_ (3 * F_) // 24576

constexpr int CAP = 101;       // per-edge cap; face clip at 100 makes this lossless
constexpr int GD  = 8;         // grid cells per axis (unit cells over [-4,4), clamped)
constexpr int NC  = GD*GD*GD;  // 512 cells
constexpr int NBLK = 256;
constexpr int TPB  = 256;
constexpr int NWAVES = NBLK * (TPB / 64); // 1024

// ws layout (498,944 B total):
//   S4        float4[E_] @ 0        (cx,cy,cz, __int_as_float(origEdge))
//   cnt       int[E_]    @ 393216
//   cellStart int[513]   @ 491520
//   cellOff   int[512]   @ 493824
//   hist      int[512]   @ 495872   (zeroed in-kernel, phase 0)
//   partial   float[256] @ 497920

__device__ __forceinline__ void edge_centroid(
    const float* __restrict__ vertices, const int* __restrict__ faces,
    int e, float& cx, float& cy, float& cz)
{
    int f, i0, i1;
    if (e < F_)        { f = e;        i0 = 0; i1 = 1; }
    else if (e < 2*F_) { f = e - F_;   i0 = 1; i1 = 2; }
    else               { f = e - 2*F_; i0 = 2; i1 = 0; }
    int a = faces[f*3 + i0];
    int b = faces[f*3 + i1];
    cx = 0.5f*(vertices[a*3+0] + vertices[b*3+0]);
    cy = 0.5f*(vertices[a*3+1] + vertices[b*3+1]);
    cz = 0.5f*(vertices[a*3+2] + vertices[b*3+2]);
}

__device__ __forceinline__ int cell_coord(float c)
{
    // monotone map -> clamped cell index; any pair with |dc|<1 stays within +-1 cell
    return min(GD-1, max(0, (int)floorf(c) + GD/2));
}

__global__ __launch_bounds__(256) void fused_kernel(
    const float* __restrict__ vertices, const int* __restrict__ faces,
    const float* __restrict__ probs,
    float4* __restrict__ S4, int* __restrict__ cnt,
    int* __restrict__ cellStart, int* __restrict__ cellOff,
    int* __restrict__ hist, float* __restrict__ partial,
    float* __restrict__ out)
{
    cg::grid_group grid = cg::this_grid();
    const int tid  = threadIdx.x;
    const int gid  = blockIdx.x * TPB + tid;
    const int lane = tid & 63;
    const int wv   = tid >> 6;

    __shared__ int   swtot[4];
    __shared__ float sred[4];

    // ---- P0: zero hist ----
    if (gid < NC) hist[gid] = 0;
    grid.sync();

    // ---- P1: centroid + cell + histogram (cx..cell persist in registers) ----
    float cx = 0.f, cy = 0.f, cz = 0.f; int cell = 0;
    if (gid < E_) {
        edge_centroid(vertices, faces, gid, cx, cy, cz);
        cell = (cell_coord(cz)*GD + cell_coord(cy))*GD + cell_coord(cx);
        atomicAdd(&hist[cell], 1);
    }
    __threadfence();
    grid.sync();

    // ---- P2: exclusive scan of hist[0..NC) in block 0 (2 cells/thread) ----
    if (blockIdx.x == 0) {
        int a0 = hist[2*tid], a1 = hist[2*tid + 1];
        int tsum = a0 + a1;
        int x = tsum;                         // wave-inclusive scan of tsum
        for (int d = 1; d < 64; d <<= 1) {
            int y = __shfl_up(x, d, 64);
            if (lane >= d) x += y;
        }
        if (lane == 63) swtot[wv] = x;
        __syncthreads();
        if (tid == 0) {
            int acc = 0;
            for (int w = 0; w < 4; w++) { int t = swtot[w]; swtot[w] = acc; acc += t; }
        }
        __syncthreads();
        int excl = x - tsum + swtot[wv];
        cellStart[2*tid]   = excl;
        cellStart[2*tid+1] = excl + a0;
        cellOff[2*tid]     = excl;
        cellOff[2*tid+1]   = excl + a0;
        if (tid == TPB - 1) cellStart[NC] = excl + tsum;
    }
    __threadfence();
    grid.sync();

    // ---- P3: counting-sort scatter ----
    if (gid < E_) {
        int pos = atomicAdd(&cellOff[cell], 1);
        S4[pos] = make_float4(cx, cy, cz, __int_as_float(gid));
    }
    __threadfence();
    grid.sync();

    // ---- P4: count — one wave per sorted position, grid-stride ----
    {
        const int wave_id = blockIdx.x * (TPB / 64) + wv;
        const float d2t = (1.0f + 1e-6f) * (1.0f + 1e-6f);
        const int DY[9] = {0,-1, 1, 0,-1, 1, 0,-1, 1};
        const int DZ[9] = {0, 0, 0,-1,-1,-1, 1, 1, 1};
        for (int p = wave_id; p < E_; p += NWAVES) {
            float4 s = S4[p];                 // wave-uniform broadcast
            const float ex = s.x, ey = s.y, ez = s.z;
            const int   e  = __float_as_int(s.w);
            const int ix = cell_coord(ex), iy = cell_coord(ey), iz = cell_coord(ez);
            const int xlo = max(ix-1, 0), xhi = min(ix+1, GD-1);
            int count = 0;
#pragma unroll
            for (int q = 0; q < 9; ++q) {
                int y = iy + DY[q], z = iz + DZ[q];
                if ((unsigned)y >= (unsigned)GD || (unsigned)z >= (unsigned)GD) continue;
                int base = (z*GD + y)*GD;
                int lo = cellStart[base + xlo];
                int hi = cellStart[base + xhi + 1];
                for (int j = lo + lane; j - lane < hi; j += 64) { // wave-uniform trips
                    float4 t = S4[min(j, E_-1)];
                    float dx = ex - t.x, dy2 = ey - t.y, dz2 = ez - t.z;
                    float d2 = dx*dx + dy2*dy2 + dz2*dz2;
                    bool c = (j < hi) && (d2 < d2t);
                    count += __popcll(__ballot(c));
                    if (count >= CAP) goto pdone;     // wave-uniform
                }
            }
        pdone:
            if (lane == 0) cnt[e] = count;
        }
    }
    __threadfence();
    grid.sync();

    // ---- P5: face reduce (two-level) ----
    float local = 0.f;
    if (gid < F_) {
        // face f's edges in the concatenated [(0,1),(1,2),(2,0)] layout
        float c = (float)(cnt[gid] + cnt[F_ + gid] + cnt[2*F_ + gid]);
        c = fminf(fmaxf(c, 0.f), 100.f);
        local = probs[gid] * c;
    }
#pragma unroll
    for (int off = 32; off > 0; off >>= 1)
        local += __shfl_down(local, off, 64);
    if (lane == 0) sred[wv] = local;
    __syncthreads();
    if (tid == 0) partial[blockIdx.x] = sred[0] + sred[1] + sred[2] + sred[3];
    __threadfence();
    grid.sync();
    if (blockIdx.x == 0) {
        float v = partial[tid];               // NBLK == TPB == 256
#pragma unroll
        for (int off = 32; off > 0; off >>= 1)
            v += __shfl_down(v, off, 64);
        if (lane == 0) sred[wv] = v;
        __syncthreads();
        if (tid == 0)
            out[0] = (sred[0] + sred[1] + sred[2] + sred[3]) / (float)F_;
    }
}

extern "C" void kernel_launch(void* const* d_in, const int* in_sizes, int n_in,
                              void* d_out, int out_size, void* d_ws, size_t ws_size,
                              hipStream_t stream)
{
    const float* vertices = (const float*)d_in[0];
    const int*   faces    = (const int*)d_in[1];   // int64 in reference -> int32 on device
    const float* probs    = (const float*)d_in[2];
    float* out = (float*)d_out;

    char* ws = (char*)d_ws;
    float4* S4        = (float4*)ws;
    int*    cnt       = (int*)(ws + 393216);
    int*    cellStart = (int*)(ws + 491520);
    int*    cellOff   = (int*)(ws + 493824);
    int*    hist      = (int*)(ws + 495872);
    float*  partial   = (float*)(ws + 497920);

    void* args[] = { (void*)&vertices, (void*)&faces, (void*)&probs,
                     (void*)&S4, (void*)&cnt, (void*)&cellStart, (void*)&cellOff,
                     (void*)&hist, (void*)&partial, (void*)&out };
    hipLaunchCooperativeKernel((const void*)fused_kernel, dim3(NBLK), dim3(TPB),
                               args, 0, stream);
}

// Round 9
// 296.012 us; speedup vs baseline: 1.3941x; 1.3941x over previous
//
#include <hip/hip_runtime.h>

#define V_ 25000
#define F_ 8192
#define E_ (3 * F_) // 24576

constexpr int CAP  = 101;      // per-edge cap; face clip at 100 makes this lossless
constexpr int GD   = 8;        // grid cells per axis (unit cells over [-4,4), clamped)
constexpr int NC   = GD*GD*GD; // 512 cells
constexpr int CAPC = 6144;     // per-cell list capacity (center cell ~4400 expected)

// ws layout:
//   C4        float4[E_]        @ 0           (cx,cy,cz, __int_as_float(cell))
//   cellList  float4[NC*CAPC]   @ 393,216     (50,331,648 B)
//   cellCount int[NC]           @ 50,724,864  (2,048 B)    \
//   facePack  uint[F_]          @ 50,726,912  (32,768 B)    | one 34,824 B memset
//   accum     float             @ 50,759,680  (4 B)         |
//   ndone     int               @ 50,759,684  (4 B)        /
constexpr size_t OFF_LIST  = 393216;
constexpr size_t OFF_CCNT  = 50724864;
constexpr size_t OFF_FPK   = 50726912;
constexpr size_t OFF_ACC   = 50759680;
constexpr size_t OFF_DONE  = 50759684;
constexpr size_t ZERO_BYTES = 2048 + 32768 + 8;

__device__ __forceinline__ int cell_coord(float c)
{
    // monotone map -> clamped cell index; any pair with |dc|<1 stays within +-1 cell
    return min(GD-1, max(0, (int)floorf(c) + GD/2));
}

// 96 blocks x 256: centroid + cell, LDS-rank counting-append into per-cell lists.
__global__ __launch_bounds__(256) void build_kernel(
    const float* __restrict__ vertices, const int* __restrict__ faces,
    float4* __restrict__ C4, float4* __restrict__ cellList,
    int* __restrict__ cellCount)
{
    __shared__ int lh[NC];
    __shared__ int lbase[NC];
    for (int i = threadIdx.x; i < NC; i += 256) lh[i] = 0;
    __syncthreads();

    const int e = blockIdx.x * 256 + threadIdx.x;
    int f, i0, i1;
    if (e < F_)        { f = e;        i0 = 0; i1 = 1; }
    else if (e < 2*F_) { f = e - F_;   i0 = 1; i1 = 2; }
    else               { f = e - 2*F_; i0 = 2; i1 = 0; }
    int a = faces[f*3 + i0];
    int b = faces[f*3 + i1];
    float cx = 0.5f*(vertices[a*3+0] + vertices[b*3+0]);
    float cy = 0.5f*(vertices[a*3+1] + vertices[b*3+1]);
    float cz = 0.5f*(vertices[a*3+2] + vertices[b*3+2]);
    int cell = (cell_coord(cz)*GD + cell_coord(cy))*GD + cell_coord(cx);
    int rank = atomicAdd(&lh[cell], 1);
    __syncthreads();
    for (int i = threadIdx.x; i < NC; i += 256) {
        int c = lh[i];
        if (c) lbase[i] = atomicAdd(&cellCount[i], c);
    }
    __syncthreads();
    C4[e] = make_float4(cx, cy, cz, __int_as_float(cell));
    cellList[(size_t)cell * CAPC + lbase[cell] + rank] = make_float4(cx, cy, cz, 0.f);
}

// One wave per edge: scan the 27 neighbor cell lists (own cell first),
// 64 candidates/iter, ballot-count, wave-uniform cap-exit at >=CAP.
// Then fused face-reduce via arrival-packed atomics.
__global__ __launch_bounds__(256) void count_kernel(
    const float4* __restrict__ C4, const float4* __restrict__ cellList,
    const int* __restrict__ cellCount, const float* __restrict__ probs,
    unsigned* __restrict__ facePack, float* __restrict__ accum,
    int* __restrict__ ndone, float* __restrict__ out)
{
    const int wave = threadIdx.x >> 6;
    const int lane = threadIdx.x & 63;
    const int e = blockIdx.x * 4 + wave;

    float4 s = C4[e];                          // wave-uniform broadcast
    const float ex = s.x, ey = s.y, ez = s.z;
    const int   cell = __float_as_int(s.w);
    const int ix = cell & 7, iy = (cell >> 3) & 7, iz = cell >> 6;
    const float d2t = (1.0f + 1e-6f) * (1.0f + 1e-6f);

    const int D[3] = {0, -1, 1};               // own offset first -> fastest capping
    int count = 0;
#pragma unroll
    for (int qz = 0; qz < 3; ++qz) {
        int z = iz + D[qz];
        if ((unsigned)z >= (unsigned)GD) continue;
#pragma unroll
        for (int qy = 0; qy < 3; ++qy) {
            int y = iy + D[qy];
            if ((unsigned)y >= (unsigned)GD) continue;
#pragma unroll
            for (int qx = 0; qx < 3; ++qx) {
                int x = ix + D[qx];
                if ((unsigned)x >= (unsigned)GD) continue;
                int nc = (z*GD + y)*GD + x;
                int n = cellCount[nc];          // wave-uniform
                const float4* __restrict__ L = cellList + (size_t)nc * CAPC;
                for (int base = 0; base < n; base += 64) {
                    int idx = base + lane;
                    float4 t = L[min(idx, n - 1)];
                    float dx = ex - t.x, dy = ey - t.y, dz = ez - t.z;
                    float d2 = dx*dx + dy*dy + dz*dz;
                    bool c = (idx < n) && (d2 < d2t);
                    count += __popcll(__ballot(c));
                    if (count >= CAP) goto done;      // wave-uniform
                }
            }
        }
    }
done:
    if (lane == 0) {
        const int fc = e & (F_ - 1);           // face id in concatenated layout
        unsigned old = atomicAdd(&facePack[fc], (unsigned)count + (1u << 22));
        if ((old >> 22) == 2u) {               // third (last) arrival for this face
            float c = (float)((old & 0x3FFFFFu) + (unsigned)count);
            c = fminf(c, 100.0f);
            atomicAdd(accum, probs[fc] * c);
            __threadfence();
            int d = atomicAdd(ndone, 1);
            if (d == F_ - 1) {                 // last face completed anywhere
                __threadfence();
                float total = atomicAdd(accum, 0.0f);  // atomic read: coherent
                out[0] = total / (float)F_;
            }
        }
    }
}

extern "C" void kernel_launch(void* const* d_in, const int* in_sizes, int n_in,
                              void* d_out, int out_size, void* d_ws, size_t ws_size,
                              hipStream_t stream)
{
    const float* vertices = (const float*)d_in[0];
    const int*   faces    = (const int*)d_in[1];   // int64 in reference -> int32 on device
    const float* probs    = (const float*)d_in[2];
    float* out = (float*)d_out;

    char* ws = (char*)d_ws;
    float4*   C4        = (float4*)ws;
    float4*   cellList  = (float4*)(ws + OFF_LIST);
    int*      cellCount = (int*)(ws + OFF_CCNT);
    unsigned* facePack  = (unsigned*)(ws + OFF_FPK);
    float*    accum     = (float*)(ws + OFF_ACC);
    int*      ndone     = (int*)(ws + OFF_DONE);

    hipMemsetAsync(ws + OFF_CCNT, 0, ZERO_BYTES, stream);
    hipLaunchKernelGGL(build_kernel, dim3(E_ / 256), dim3(256), 0, stream,
                       vertices, faces, C4, cellList, cellCount);
    hipLaunchKernelGGL(count_kernel, dim3(E_ / 4), dim3(256), 0, stream,
                       C4, cellList, cellCount, probs, facePack, accum, ndone, out);
}

// Round 10
// 103.617 us; speedup vs baseline: 3.9825x; 2.8568x over previous
//
#include <hip/hip_runtime.h>

#define V_ 25000
#define F_ 8192
#define E_ (3 * F_) // 24576

constexpr int CAP  = 101;      // per-edge cap; face clip at 100 makes this lossless
constexpr int GD   = 8;        // grid cells per axis (unit cells over [-4,4), clamped)
constexpr int NC   = GD*GD*GD; // 512 cells
constexpr int CAPC = 6144;     // per-cell list capacity (center cell ~4400 expected)

// ws layout:
//   C4        float4[E_]        @ 0           (cx,cy,cz, __int_as_float(cell))
//   cellList  float4[NC*CAPC]   @ 393,216     (50,331,648 B)
//   cellCount int[NC]           @ 50,724,864  (2,048 B — the only memset)
//   cnt       int[E_]           @ 50,726,912  (98,304 B — fully overwritten)
constexpr size_t OFF_LIST = 393216;
constexpr size_t OFF_CCNT = 50724864;
constexpr size_t OFF_CNT  = 50726912;

__device__ __forceinline__ int cell_coord(float c)
{
    // monotone map -> clamped cell index; any pair with |dc|<1 stays within +-1 cell
    return min(GD-1, max(0, (int)floorf(c) + GD/2));
}

// 96 blocks x 256: centroid + cell, LDS-rank counting-append into per-cell lists.
__global__ __launch_bounds__(256) void build_kernel(
    const float* __restrict__ vertices, const int* __restrict__ faces,
    float4* __restrict__ C4, float4* __restrict__ cellList,
    int* __restrict__ cellCount)
{
    __shared__ int lh[NC];
    __shared__ int lbase[NC];
    for (int i = threadIdx.x; i < NC; i += 256) lh[i] = 0;
    __syncthreads();

    const int e = blockIdx.x * 256 + threadIdx.x;
    int f, i0, i1;
    if (e < F_)        { f = e;        i0 = 0; i1 = 1; }
    else if (e < 2*F_) { f = e - F_;   i0 = 1; i1 = 2; }
    else               { f = e - 2*F_; i0 = 2; i1 = 0; }
    int a = faces[f*3 + i0];
    int b = faces[f*3 + i1];
    float cx = 0.5f*(vertices[a*3+0] + vertices[b*3+0]);
    float cy = 0.5f*(vertices[a*3+1] + vertices[b*3+1]);
    float cz = 0.5f*(vertices[a*3+2] + vertices[b*3+2]);
    int cell = (cell_coord(cz)*GD + cell_coord(cy))*GD + cell_coord(cx);
    int rank = atomicAdd(&lh[cell], 1);
    __syncthreads();
    for (int i = threadIdx.x; i < NC; i += 256) {
        int c = lh[i];
        if (c) lbase[i] = atomicAdd(&cellCount[i], c);
    }
    __syncthreads();
    C4[e] = make_float4(cx, cy, cz, __int_as_float(cell));
    cellList[(size_t)cell * CAPC + lbase[cell] + rank] = make_float4(cx, cy, cz, 0.f);
}

// One wave per edge: scan the 27 neighbor cell lists (own cell first),
// 64 candidates/iter, ballot-count, wave-uniform cap-exit at >=CAP.
// One plain store per wave — no cross-wave atomics anywhere.
__global__ __launch_bounds__(256) void count_kernel(
    const float4* __restrict__ C4, const float4* __restrict__ cellList,
    const int* __restrict__ cellCount, int* __restrict__ cnt)
{
    const int wave = threadIdx.x >> 6;
    const int lane = threadIdx.x & 63;
    const int e = blockIdx.x * 4 + wave;

    float4 s = C4[e];                          // wave-uniform broadcast
    const float ex = s.x, ey = s.y, ez = s.z;
    const int   cell = __float_as_int(s.w);
    const int ix = cell & 7, iy = (cell >> 3) & 7, iz = cell >> 6;
    const float d2t = (1.0f + 1e-6f) * (1.0f + 1e-6f);

    const int D[3] = {0, -1, 1};               // own offset first -> fastest capping
    int count = 0;
#pragma unroll
    for (int qz = 0; qz < 3; ++qz) {
        int z = iz + D[qz];
        if ((unsigned)z >= (unsigned)GD) continue;
#pragma unroll
        for (int qy = 0; qy < 3; ++qy) {
            int y = iy + D[qy];
            if ((unsigned)y >= (unsigned)GD) continue;
#pragma unroll
            for (int qx = 0; qx < 3; ++qx) {
                int x = ix + D[qx];
                if ((unsigned)x >= (unsigned)GD) continue;
                int nc = (z*GD + y)*GD + x;
                int n = cellCount[nc];          // wave-uniform
                const float4* __restrict__ L = cellList + (size_t)nc * CAPC;
                for (int base = 0; base < n; base += 64) {
                    int idx = base + lane;
                    float4 t = L[min(idx, n - 1)];
                    float dx = ex - t.x, dy = ey - t.y, dz = ez - t.z;
                    float d2 = dx*dx + dy*dy + dz*dz;
                    bool c = (idx < n) && (d2 < d2t);
                    count += __popcll(__ballot(c));
                    if (count >= CAP) goto done;      // wave-uniform
                }
            }
        }
    }
done:
    if (lane == 0) cnt[e] = count;
}

__global__ __launch_bounds__(1024) void reduce_kernel(
    const int* __restrict__ cnt, const float* __restrict__ probs,
    float* __restrict__ out)
{
    float local = 0.0f;
    for (int f = threadIdx.x; f < F_; f += 1024) {
        // face f's edges in the concatenated [(0,1),(1,2),(2,0)] layout
        float c = (float)(cnt[f] + cnt[F_ + f] + cnt[2*F_ + f]);
        c = fminf(fmaxf(c, 0.0f), 100.0f);
        local += probs[f] * c;
    }
#pragma unroll
    for (int off = 32; off > 0; off >>= 1)
        local += __shfl_down(local, off, 64);
    __shared__ float wsum[16];
    if ((threadIdx.x & 63) == 0) wsum[threadIdx.x >> 6] = local;
    __syncthreads();
    if (threadIdx.x == 0) {
        float t = 0.0f;
#pragma unroll
        for (int w = 0; w < 16; w++) t += wsum[w];
        out[0] = t / (float)F_;
    }
}

extern "C" void kernel_launch(void* const* d_in, const int* in_sizes, int n_in,
                              void* d_out, int out_size, void* d_ws, size_t ws_size,
                              hipStream_t stream)
{
    const float* vertices = (const float*)d_in[0];
    const int*   faces    = (const int*)d_in[1];   // int64 in reference -> int32 on device
    const float* probs    = (const float*)d_in[2];
    float* out = (float*)d_out;

    char* ws = (char*)d_ws;
    float4* C4        = (float4*)ws;
    float4* cellList  = (float4*)(ws + OFF_LIST);
    int*    cellCount = (int*)(ws + OFF_CCNT);
    int*    cnt       = (int*)(ws + OFF_CNT);

    hipMemsetAsync(cellCount, 0, NC * sizeof(int), stream);
    hipLaunchKernelGGL(build_kernel, dim3(E_ / 256), dim3(256), 0, stream,
                       vertices, faces, C4, cellList, cellCount);
    hipLaunchKernelGGL(count_kernel, dim3(E_ / 4), dim3(256), 0, stream,
                       C4, cellList, cellCount, cnt);
    hipLaunchKernelGGL(reduce_kernel, dim3(1), dim3(1024), 0, stream,
                       cnt, probs, out);
}